// Round 7
// baseline (269.118 us; speedup 1.0000x reference)
//
#include <hip/hip_runtime.h>

typedef unsigned int   u32;
typedef unsigned short u16;
typedef float f32x4  __attribute__((ext_vector_type(4)));
typedef short bf16x8 __attribute__((ext_vector_type(8)));
typedef u32   u32x4  __attribute__((ext_vector_type(4)));
typedef u32   u32x2  __attribute__((ext_vector_type(2)));

#define EPS 1e-5f
#define MT 4800

// single-instruction RNE pack of two f32 -> packed bf16x2 (T12 recipe; no builtin on gfx950)
__device__ __forceinline__ u32 cvtpk(float lo, float hi) {
    u32 r;
    asm("v_cvt_pk_bf16_f32 %0, %1, %2" : "=v"(r) : "v"(lo), "v"(hi));
    return r;
}
__device__ __forceinline__ float bflo(u32 p) { union { u32 i; float f; } x; x.i = p << 16; return x.f; }
__device__ __forceinline__ float bfhi(u32 p) { union { u32 i; float f; } x; x.i = p & 0xffff0000u; return x.f; }

union UU { u32x4 u; bf16x8 b; };

__device__ __forceinline__ bf16x8 pack8(const float* __restrict__ p) {
    UU x;
    x.u = (u32x4){cvtpk(p[0], p[1]), cvtpk(p[2], p[3]), cvtpk(p[4], p[5]), cvtpk(p[6], p[7])};
    return x.b;
}
__device__ __forceinline__ bf16x8 pack8s(const float* __restrict__ p, float s) {
    UU x;
    x.u = (u32x4){cvtpk(s*p[0], s*p[1]), cvtpk(s*p[2], s*p[3]),
                  cvtpk(s*p[4], s*p[5]), cvtpk(s*p[6], s*p[7])};
    return x.b;
}

// stage layout (u16 units): A0'[64k][72c] @0 (stride 72, 16B-aligned rows for b128)
//                           C1''[64c][68k] @4608, CSK[64c][68k] @8960 (stride 68, b64 reads)
#define C1_OFF 4608
#define CS_OFF 8960

__global__ __launch_bounds__(256, 4) void ctx_fused(
    const float* __restrict__ q, const float* __restrict__ srgb,
    const float* __restrict__ sxyz, const float* __restrict__ prexyz,
    const float* __restrict__ mask,
    const float* __restrict__ W0,
    const float* __restrict__ g0, const float* __restrict__ b0,
    const float* __restrict__ m0_, const float* __restrict__ v0_,
    const float* __restrict__ W1a,
    const float* __restrict__ g1a, const float* __restrict__ b1a,
    const float* __restrict__ m1a, const float* __restrict__ v1a,
    const float* __restrict__ W1b,
    const float* __restrict__ g1b, const float* __restrict__ b1b,
    const float* __restrict__ m1b, const float* __restrict__ v1b,
    const float* __restrict__ Wsk, const float* __restrict__ Wout,
    float* __restrict__ out)
{
    const int tid = threadIdx.x;
    const int w = tid >> 6, l = tid & 63;
    const int g = l >> 4, kidx = l & 15;
    const int mg = blockIdx.x, n = blockIdx.y;
    const int m0 = mg * 16;

    __shared__ u16  stage[13312];      // 26624 B
    __shared__ u16  h1s[4][16 * 72];   // 9216 B, per-wave h1 repack scratch
    __shared__ float Bs[16 * 64];      // 4096 B: B' = s0 * (W0q @ q), [m][c]

    // ---- prep A: resident weight fragments (s1a folded into w1a, s1b into w1b) ----
    bf16x8 w1a[8], wsk[8], w1b[8];
    #pragma unroll
    for (int ct = 0; ct < 4; ++ct) {
        int c = ct * 16 + kidx;
        float s1a = g1a[c] * rsqrtf(v1a[c] + EPS);
        float s1b = g1b[c] * rsqrtf(v1b[c] + EPS);
        #pragma unroll
        for (int t = 0; t < 2; ++t) {
            int j0 = t * 32 + g * 8;
            w1a[ct * 2 + t] = pack8s(W1a + c * 67 + j0, s1a);
            wsk[ct * 2 + t] = pack8 (Wsk + c * 67 + j0);
            w1b[ct * 2 + t] = pack8s(W1b + c * 64 + j0, s1b);
        }
    }

    // ---- prep B: A0' = bn0-fold(W0rgb @ srgb[n]); wave w fills k-rows 16w..16w+15 ----
    {
        f32x4 acc[4];
        #pragma unroll
        for (int ct = 0; ct < 4; ++ct) acc[ct] = 0.f;
        #pragma unroll
        for (int t = 0; t < 2; ++t) {
            float se[8];
            #pragma unroll
            for (int e = 0; e < 8; ++e) {
                int j = t * 32 + g * 8 + e;
                se[e] = srgb[(n * 64 + j) * 64 + w * 16 + kidx];
            }
            UU a; a.u = (u32x4){cvtpk(se[0], se[1]), cvtpk(se[2], se[3]),
                                cvtpk(se[4], se[5]), cvtpk(se[6], se[7])};
            #pragma unroll
            for (int ct = 0; ct < 4; ++ct) {
                bf16x8 wb = pack8(W0 + (ct * 16 + kidx) * 128 + t * 32 + g * 8);
                acc[ct] = __builtin_amdgcn_mfma_f32_16x16x32_bf16(a.b, wb, acc[ct], 0, 0, 0);
            }
        }
        #pragma unroll
        for (int ct = 0; ct < 4; ++ct) {
            int c = ct * 16 + kidx;
            float s0 = g0[c] * rsqrtf(v0_[c] + EPS);
            float t0 = b0[c] - m0_[c] * s0;
            u32 p01 = cvtpk(s0 * acc[ct][0] + t0, s0 * acc[ct][1] + t0);
            u32 p23 = cvtpk(s0 * acc[ct][2] + t0, s0 * acc[ct][3] + t0);
            int kb = w * 16 + g * 4;
            stage[(kb + 0) * 72 + c] = (u16)p01;
            stage[(kb + 1) * 72 + c] = (u16)(p01 >> 16);
            stage[(kb + 2) * 72 + c] = (u16)p23;
            stage[(kb + 3) * 72 + c] = (u16)(p23 >> 16);
        }
    }

    // ---- prep C: C1'' and CSK (tid -> channel c, 16 consecutive k), stride 68 ----
    {
        int c  = tid & 63;
        int kq = tid >> 6;
        float s1a = g1a[c] * rsqrtf(v1a[c] + EPS);
        float t1a = b1a[c] - m1a[c] * s1a;
        float wa0 = W1a[c * 67 + 64], wa1 = W1a[c * 67 + 65], wa2 = W1a[c * 67 + 66];
        float wsa = Wsk[c * 67 + 64], wsb = Wsk[c * 67 + 65], wsc = Wsk[c * 67 + 66];
        u32* d1 = (u32*)(stage + C1_OFF + c * 68 + kq * 16);
        u32* d2 = (u32*)(stage + CS_OFF + c * 68 + kq * 16);
        #pragma unroll
        for (int p = 0; p < 8; ++p) {
            float v[2], s[2];
            #pragma unroll
            for (int h = 0; h < 2; ++h) {
                int k = kq * 16 + p * 2 + h;
                float mk = mask[n * 64 + k];
                float x0 = sxyz[(n * 3 + 0) * 64 + k] * mk;
                float x1 = sxyz[(n * 3 + 1) * 64 + k] * mk;
                float x2 = sxyz[(n * 3 + 2) * 64 + k] * mk;
                v[h] = s1a * (wa0 * x0 + wa1 * x1 + wa2 * x2) + t1a;
                s[h] = wsa * x0 + wsb * x1 + wsc * x2;
            }
            d1[p] = cvtpk(v[0], v[1]);
            d2[p] = cvtpk(s[0], s[1]);
        }
    }

    // ---- prep D: wave 0: B' GEMM (16 m rows x 64 c, K = 64 q-channels) ----
    if (w == 0) {
        f32x4 acc0[4];
        #pragma unroll
        for (int ct = 0; ct < 4; ++ct) acc0[ct] = 0.f;
        #pragma unroll
        for (int t = 0; t < 2; ++t) {
            float qe[8];
            #pragma unroll
            for (int e = 0; e < 8; ++e)
                qe[e] = q[(n * 64 + t * 32 + g * 8 + e) * MT + m0 + kidx];
            UU a; a.u = (u32x4){cvtpk(qe[0], qe[1]), cvtpk(qe[2], qe[3]),
                                cvtpk(qe[4], qe[5]), cvtpk(qe[6], qe[7])};
            #pragma unroll
            for (int ct = 0; ct < 4; ++ct) {
                bf16x8 wb = pack8(W0 + (ct * 16 + kidx) * 128 + 64 + t * 32 + g * 8);
                acc0[ct] = __builtin_amdgcn_mfma_f32_16x16x32_bf16(a.b, wb, acc0[ct], 0, 0, 0);
            }
        }
        #pragma unroll
        for (int ct = 0; ct < 4; ++ct) {
            int c = ct * 16 + kidx;
            float s0 = g0[c] * rsqrtf(v0_[c] + EPS);
            #pragma unroll
            for (int r = 0; r < 4; ++r)
                Bs[(g * 4 + r) * 64 + c] = s0 * acc0[ct][r];
        }
    }

    // per-lane folded scalars (c = 16*ct + kidx)
    float t1b_r[4], wo0[4], wo1[4], wo2[4];
    #pragma unroll
    for (int ct = 0; ct < 4; ++ct) {
        int c = ct * 16 + kidx;
        float s1b = g1b[c] * rsqrtf(v1b[c] + EPS);
        t1b_r[ct] = b1b[c] - m1b[c] * s1b;
        wo0[ct] = Wout[0 * 67 + c];
        wo1[ct] = Wout[1 * 67 + c];
        wo2[ct] = Wout[2 * 67 + c];
    }

    __syncthreads();   // stage + Bs ready

    const u16* A0p = stage;            // [k][72]
    const u16* C1p = stage + C1_OFF;   // [c][68]
    const u16* CSp = stage + CS_OFF;   // [c][68]
    u16* h1p = h1s[w];

    #pragma unroll 1
    for (int i = 0; i < 4; ++i) {
        const int m = m0 + w * 4 + i;

        float bfr[2][8];
        #pragma unroll
        for (int t = 0; t < 2; ++t)
            #pragma unroll
            for (int e = 0; e < 8; ++e)
                bfr[t][e] = Bs[(w * 4 + i) * 64 + t * 32 + g * 8 + e];

        float fmr[4];
        #pragma unroll
        for (int ct = 0; ct < 4; ++ct) fmr[ct] = -3.0e38f;

        for (int s = 0; s < 4; ++s) {   // 4 strips of 16 k-points
            // h0 A-fragments built directly in fragment layout
            bf16x8 af[2];
            #pragma unroll
            for (int t = 0; t < 2; ++t) {
                u32x4 a = *(const u32x4*)(A0p + (s * 16 + kidx) * 72 + t * 32 + g * 8);
                float h[8];
                h[0] = bflo(a[0]); h[1] = bfhi(a[0]); h[2] = bflo(a[1]); h[3] = bfhi(a[1]);
                h[4] = bflo(a[2]); h[5] = bfhi(a[2]); h[6] = bflo(a[3]); h[7] = bfhi(a[3]);
                #pragma unroll
                for (int e = 0; e < 8; ++e) h[e] = fmaxf(h[e] + bfr[t][e], 0.f);
                UU x; x.u = (u32x4){cvtpk(h[0], h[1]), cvtpk(h[2], h[3]),
                                    cvtpk(h[4], h[5]), cvtpk(h[6], h[7])};
                af[t] = x.b;
            }
            // acc init from C1'' / CSK (accumulator-init trick: saves epilogue FMAs)
            f32x4 acc1[4], accS[4];
            #pragma unroll
            for (int ct = 0; ct < 4; ++ct) {
                int c = ct * 16 + kidx;
                u32x2 cv1 = *(const u32x2*)(C1p + c * 68 + s * 16 + g * 4);
                u32x2 cvs = *(const u32x2*)(CSp + c * 68 + s * 16 + g * 4);
                acc1[ct] = (f32x4){bflo(cv1[0]), bfhi(cv1[0]), bflo(cv1[1]), bfhi(cv1[1])};
                accS[ct] = (f32x4){bflo(cvs[0]), bfhi(cvs[0]), bflo(cvs[1]), bfhi(cvs[1])};
            }
            // stage1 + skip GEMMs (s1a pre-folded into w1a)
            #pragma unroll
            for (int t = 0; t < 2; ++t)
                #pragma unroll
                for (int ct = 0; ct < 4; ++ct)
                    acc1[ct] = __builtin_amdgcn_mfma_f32_16x16x32_bf16(af[t], w1a[ct * 2 + t], acc1[ct], 0, 0, 0);
            #pragma unroll
            for (int t = 0; t < 2; ++t)
                #pragma unroll
                for (int ct = 0; ct < 4; ++ct)
                    accS[ct] = __builtin_amdgcn_mfma_f32_16x16x32_bf16(af[t], wsk[ct * 2 + t], accS[ct], 0, 0, 0);

            // h1 = relu(acc1) -> per-wave LDS (D-layout -> A-layout repack)
            #pragma unroll
            for (int ct = 0; ct < 4; ++ct) {
                int c = ct * 16 + kidx;
                u32 p01 = cvtpk(fmaxf(acc1[ct][0], 0.f), fmaxf(acc1[ct][1], 0.f));
                u32 p23 = cvtpk(fmaxf(acc1[ct][2], 0.f), fmaxf(acc1[ct][3], 0.f));
                h1p[(g * 4 + 0) * 72 + c] = (u16)p01;
                h1p[(g * 4 + 1) * 72 + c] = (u16)(p01 >> 16);
                h1p[(g * 4 + 2) * 72 + c] = (u16)p23;
                h1p[(g * 4 + 3) * 72 + c] = (u16)(p23 >> 16);
            }
            // stage2 GEMM from repacked h1 (s1b pre-folded into w1b)
            f32x4 acc2[4];
            #pragma unroll
            for (int ct = 0; ct < 4; ++ct) acc2[ct] = 0.f;
            #pragma unroll
            for (int t = 0; t < 2; ++t) {
                UU x; x.u = *(const u32x4*)(h1p + kidx * 72 + t * 32 + g * 8);
                #pragma unroll
                for (int ct = 0; ct < 4; ++ct)
                    acc2[ct] = __builtin_amdgcn_mfma_f32_16x16x32_bf16(x.b, w1b[ct * 2 + t], acc2[ct], 0, 0, 0);
            }
            // feat = accS + relu(acc2 + t1b);  running max over rows (k-points)
            #pragma unroll
            for (int ct = 0; ct < 4; ++ct) {
                #pragma unroll
                for (int r = 0; r < 4; ++r) {
                    float f = accS[ct][r] + fmaxf(acc2[ct][r] + t1b_r[ct], 0.f);
                    fmr[ct] = fmaxf(fmr[ct], f);
                }
            }
        }

        // finish pool across lane groups, then out = Wout @ [featmax; prexyz]
        #pragma unroll
        for (int ct = 0; ct < 4; ++ct) {
            fmr[ct] = fmaxf(fmr[ct], __shfl_xor(fmr[ct], 16));
            fmr[ct] = fmaxf(fmr[ct], __shfl_xor(fmr[ct], 32));
        }
        float po0 = 0.f, po1 = 0.f, po2 = 0.f;
        #pragma unroll
        for (int ct = 0; ct < 4; ++ct) {
            po0 += wo0[ct] * fmr[ct];
            po1 += wo1[ct] * fmr[ct];
            po2 += wo2[ct] * fmr[ct];
        }
        #pragma unroll
        for (int d = 1; d <= 8; d <<= 1) {
            po0 += __shfl_xor(po0, d);
            po1 += __shfl_xor(po1, d);
            po2 += __shfl_xor(po2, d);
        }
        if (l < 3) {
            float p0 = prexyz[(n * 3 + 0) * MT + m];
            float p1 = prexyz[(n * 3 + 1) * MT + m];
            float p2 = prexyz[(n * 3 + 2) * MT + m];
            float o = (l == 0) ? po0 : ((l == 1) ? po1 : po2);
            o += Wout[l * 67 + 64] * p0 + Wout[l * 67 + 65] * p1 + Wout[l * 67 + 66] * p2;
            out[(n * 3 + l) * MT + m] = o;
        }
    }
}

extern "C" void kernel_launch(void* const* d_in, const int* in_sizes, int n_in,
                              void* d_out, int out_size, void* d_ws, size_t ws_size,
                              hipStream_t stream) {
    const float* q    = (const float*)d_in[0];
    const float* srgb = (const float*)d_in[1];
    const float* sxyz = (const float*)d_in[2];
    const float* pxyz = (const float*)d_in[3];
    const float* mask = (const float*)d_in[4];
    const float* W0   = (const float*)d_in[5];
    const float* g0   = (const float*)d_in[6];
    const float* b0   = (const float*)d_in[7];
    const float* m0   = (const float*)d_in[8];
    const float* v0   = (const float*)d_in[9];
    const float* W1a  = (const float*)d_in[10];
    const float* g1a  = (const float*)d_in[11];
    const float* b1a  = (const float*)d_in[12];
    const float* m1a  = (const float*)d_in[13];
    const float* v1a  = (const float*)d_in[14];
    const float* W1b  = (const float*)d_in[15];
    const float* g1b  = (const float*)d_in[16];
    const float* b1b  = (const float*)d_in[17];
    const float* m1b  = (const float*)d_in[18];
    const float* v1b  = (const float*)d_in[19];
    const float* Wsk  = (const float*)d_in[20];
    const float* Wout = (const float*)d_in[21];
    float* out = (float*)d_out;

    hipLaunchKernelGGL(ctx_fused, dim3(300, 2), dim3(256), 0, stream,
        q, srgb, sxyz, pxyz, mask,
        W0, g0, b0, m0, v0,
        W1a, g1a, b1a, m1a, v1a,
        W1b, g1b, b1b, m1b, v1b,
        Wsk, Wout, out);
}

// Round 9
// 149.678 us; speedup vs baseline: 1.7980x; 1.7980x over previous
//
#include <hip/hip_runtime.h>

typedef unsigned int   u32;
typedef unsigned short u16;
typedef float f32x4  __attribute__((ext_vector_type(4)));
typedef short bf16x8 __attribute__((ext_vector_type(8)));
typedef u32   u32x4  __attribute__((ext_vector_type(4)));
typedef u32   u32x2  __attribute__((ext_vector_type(2)));

#define EPS 1e-5f
#define MT 4800

// single-instruction RNE pack of two f32 -> packed bf16x2 (T12 recipe; no builtin on gfx950)
__device__ __forceinline__ u32 cvtpk(float lo, float hi) {
    u32 r;
    asm("v_cvt_pk_bf16_f32 %0, %1, %2" : "=v"(r) : "v"(lo), "v"(hi));
    return r;
}
__device__ __forceinline__ float bflo(u32 p) { union { u32 i; float f; } x; x.i = p << 16; return x.f; }
__device__ __forceinline__ float bfhi(u32 p) { union { u32 i; float f; } x; x.i = p & 0xffff0000u; return x.f; }

union UU { u32x4 u; bf16x8 b; };

__device__ __forceinline__ bf16x8 pack8(const float* __restrict__ p) {
    UU x;
    x.u = (u32x4){cvtpk(p[0], p[1]), cvtpk(p[2], p[3]), cvtpk(p[4], p[5]), cvtpk(p[6], p[7])};
    return x.b;
}
__device__ __forceinline__ bf16x8 pack8s(const float* __restrict__ p, float s) {
    UU x;
    x.u = (u32x4){cvtpk(s*p[0], s*p[1]), cvtpk(s*p[2], s*p[3]),
                  cvtpk(s*p[4], s*p[5]), cvtpk(s*p[6], s*p[7])};
    return x.b;
}

// stage layout (u16 units): A0'[64k][72c] @0 (stride 72, 16B-aligned rows for b128)
//                           C1''[64c][68k] @4608, CSK[64c][68k] @8960 (stride 68, b64 reads)
#define C1_OFF 4608
#define CS_OFF 8960

// NOTE: plain __launch_bounds__(256). The (256,4) variant forced VGPR->64 and
// spilled 96 regs of weight fragments to scratch (R7: FETCH 3MB->337MB, 3.4x slower).
__global__ __launch_bounds__(256) void ctx_fused(
    const float* __restrict__ q, const float* __restrict__ srgb,
    const float* __restrict__ sxyz, const float* __restrict__ prexyz,
    const float* __restrict__ mask,
    const float* __restrict__ W0,
    const float* __restrict__ g0, const float* __restrict__ b0,
    const float* __restrict__ m0_, const float* __restrict__ v0_,
    const float* __restrict__ W1a,
    const float* __restrict__ g1a, const float* __restrict__ b1a,
    const float* __restrict__ m1a, const float* __restrict__ v1a,
    const float* __restrict__ W1b,
    const float* __restrict__ g1b, const float* __restrict__ b1b,
    const float* __restrict__ m1b, const float* __restrict__ v1b,
    const float* __restrict__ Wsk, const float* __restrict__ Wout,
    float* __restrict__ out)
{
    const int tid = threadIdx.x;
    const int w = tid >> 6, l = tid & 63;
    const int g = l >> 4, kidx = l & 15;
    const int mg = blockIdx.x, n = blockIdx.y;
    const int m0 = mg * 8;             // 8 m per block (1200 blocks -> ~4 blocks/CU resident)

    __shared__ u16  stage[13312];      // 26624 B
    __shared__ u16  h1s[4][16 * 72];   // 9216 B, per-wave h1 repack scratch
    __shared__ float Bs[16 * 64];      // 4096 B: B' = s0 * (W0q @ q), [m][c] (rows 8..15 unused)
    // total 39936 B -> 4 blocks/CU by LDS

    // ---- prep A: resident weight fragments (s1a folded into w1a, s1b into w1b) ----
    bf16x8 w1a[8], wsk[8], w1b[8];
    #pragma unroll
    for (int ct = 0; ct < 4; ++ct) {
        int c = ct * 16 + kidx;
        float s1a = g1a[c] * rsqrtf(v1a[c] + EPS);
        float s1b = g1b[c] * rsqrtf(v1b[c] + EPS);
        #pragma unroll
        for (int t = 0; t < 2; ++t) {
            int j0 = t * 32 + g * 8;
            w1a[ct * 2 + t] = pack8s(W1a + c * 67 + j0, s1a);
            wsk[ct * 2 + t] = pack8 (Wsk + c * 67 + j0);
            w1b[ct * 2 + t] = pack8s(W1b + c * 64 + j0, s1b);
        }
    }

    // ---- prep B: A0' = bn0-fold(W0rgb @ srgb[n]); wave w fills k-rows 16w..16w+15 ----
    {
        f32x4 acc[4];
        #pragma unroll
        for (int ct = 0; ct < 4; ++ct) acc[ct] = 0.f;
        #pragma unroll
        for (int t = 0; t < 2; ++t) {
            float se[8];
            #pragma unroll
            for (int e = 0; e < 8; ++e) {
                int j = t * 32 + g * 8 + e;
                se[e] = srgb[(n * 64 + j) * 64 + w * 16 + kidx];
            }
            UU a; a.u = (u32x4){cvtpk(se[0], se[1]), cvtpk(se[2], se[3]),
                                cvtpk(se[4], se[5]), cvtpk(se[6], se[7])};
            #pragma unroll
            for (int ct = 0; ct < 4; ++ct) {
                bf16x8 wb = pack8(W0 + (ct * 16 + kidx) * 128 + t * 32 + g * 8);
                acc[ct] = __builtin_amdgcn_mfma_f32_16x16x32_bf16(a.b, wb, acc[ct], 0, 0, 0);
            }
        }
        #pragma unroll
        for (int ct = 0; ct < 4; ++ct) {
            int c = ct * 16 + kidx;
            float s0 = g0[c] * rsqrtf(v0_[c] + EPS);
            float t0 = b0[c] - m0_[c] * s0;
            u32 p01 = cvtpk(s0 * acc[ct][0] + t0, s0 * acc[ct][1] + t0);
            u32 p23 = cvtpk(s0 * acc[ct][2] + t0, s0 * acc[ct][3] + t0);
            int kb = w * 16 + g * 4;
            stage[(kb + 0) * 72 + c] = (u16)p01;
            stage[(kb + 1) * 72 + c] = (u16)(p01 >> 16);
            stage[(kb + 2) * 72 + c] = (u16)p23;
            stage[(kb + 3) * 72 + c] = (u16)(p23 >> 16);
        }
    }

    // ---- prep C: C1'' and CSK (tid -> channel c, 16 consecutive k), stride 68 ----
    {
        int c  = tid & 63;
        int kq = tid >> 6;
        float s1a = g1a[c] * rsqrtf(v1a[c] + EPS);
        float t1a = b1a[c] - m1a[c] * s1a;
        float wa0 = W1a[c * 67 + 64], wa1 = W1a[c * 67 + 65], wa2 = W1a[c * 67 + 66];
        float wsa = Wsk[c * 67 + 64], wsb = Wsk[c * 67 + 65], wsc = Wsk[c * 67 + 66];
        u32* d1 = (u32*)(stage + C1_OFF + c * 68 + kq * 16);
        u32* d2 = (u32*)(stage + CS_OFF + c * 68 + kq * 16);
        #pragma unroll
        for (int p = 0; p < 8; ++p) {
            float v[2], s[2];
            #pragma unroll
            for (int h = 0; h < 2; ++h) {
                int k = kq * 16 + p * 2 + h;
                float mk = mask[n * 64 + k];
                float x0 = sxyz[(n * 3 + 0) * 64 + k] * mk;
                float x1 = sxyz[(n * 3 + 1) * 64 + k] * mk;
                float x2 = sxyz[(n * 3 + 2) * 64 + k] * mk;
                v[h] = s1a * (wa0 * x0 + wa1 * x1 + wa2 * x2) + t1a;
                s[h] = wsa * x0 + wsb * x1 + wsc * x2;
            }
            d1[p] = cvtpk(v[0], v[1]);
            d2[p] = cvtpk(s[0], s[1]);
        }
    }

    // ---- prep D: wave 0: B' GEMM (m rows x 64 c, K = 64 q-channels) ----
    if (w == 0) {
        f32x4 acc0[4];
        #pragma unroll
        for (int ct = 0; ct < 4; ++ct) acc0[ct] = 0.f;
        int mq = m0 + kidx;                 // rows 8..15 are dummies; clamp to stay in-bounds
        if (mq > MT - 1) mq = MT - 1;
        #pragma unroll
        for (int t = 0; t < 2; ++t) {
            float qe[8];
            #pragma unroll
            for (int e = 0; e < 8; ++e)
                qe[e] = q[(n * 64 + t * 32 + g * 8 + e) * MT + mq];
            UU a; a.u = (u32x4){cvtpk(qe[0], qe[1]), cvtpk(qe[2], qe[3]),
                                cvtpk(qe[4], qe[5]), cvtpk(qe[6], qe[7])};
            #pragma unroll
            for (int ct = 0; ct < 4; ++ct) {
                bf16x8 wb = pack8(W0 + (ct * 16 + kidx) * 128 + 64 + t * 32 + g * 8);
                acc0[ct] = __builtin_amdgcn_mfma_f32_16x16x32_bf16(a.b, wb, acc0[ct], 0, 0, 0);
            }
        }
        #pragma unroll
        for (int ct = 0; ct < 4; ++ct) {
            int c = ct * 16 + kidx;
            float s0 = g0[c] * rsqrtf(v0_[c] + EPS);
            #pragma unroll
            for (int r = 0; r < 4; ++r)
                Bs[(g * 4 + r) * 64 + c] = s0 * acc0[ct][r];
        }
    }

    // per-lane folded scalars (c = 16*ct + kidx)
    float t1b_r[4], wo0[4], wo1[4], wo2[4];
    #pragma unroll
    for (int ct = 0; ct < 4; ++ct) {
        int c = ct * 16 + kidx;
        float s1b = g1b[c] * rsqrtf(v1b[c] + EPS);
        t1b_r[ct] = b1b[c] - m1b[c] * s1b;
        wo0[ct] = Wout[0 * 67 + c];
        wo1[ct] = Wout[1 * 67 + c];
        wo2[ct] = Wout[2 * 67 + c];
    }

    __syncthreads();   // stage + Bs ready

    const u16* A0p = stage;            // [k][72]
    const u16* C1p = stage + C1_OFF;   // [c][68]
    const u16* CSp = stage + CS_OFF;   // [c][68]
    u16* h1p = h1s[w];

    #pragma unroll 1
    for (int i = 0; i < 2; ++i) {      // each wave: 2 m
        const int m = m0 + w * 2 + i;

        float bfr[2][8];
        #pragma unroll
        for (int t = 0; t < 2; ++t)
            #pragma unroll
            for (int e = 0; e < 8; ++e)
                bfr[t][e] = Bs[(w * 2 + i) * 64 + t * 32 + g * 8 + e];

        float fmr[4];
        #pragma unroll
        for (int ct = 0; ct < 4; ++ct) fmr[ct] = -3.0e38f;

        for (int s = 0; s < 4; ++s) {   // 4 strips of 16 k-points
            // h0 A-fragments built directly in fragment layout
            bf16x8 af[2];
            #pragma unroll
            for (int t = 0; t < 2; ++t) {
                u32x4 a = *(const u32x4*)(A0p + (s * 16 + kidx) * 72 + t * 32 + g * 8);
                float h[8];
                h[0] = bflo(a[0]); h[1] = bfhi(a[0]); h[2] = bflo(a[1]); h[3] = bfhi(a[1]);
                h[4] = bflo(a[2]); h[5] = bfhi(a[2]); h[6] = bflo(a[3]); h[7] = bfhi(a[3]);
                #pragma unroll
                for (int e = 0; e < 8; ++e) h[e] = fmaxf(h[e] + bfr[t][e], 0.f);
                UU x; x.u = (u32x4){cvtpk(h[0], h[1]), cvtpk(h[2], h[3]),
                                    cvtpk(h[4], h[5]), cvtpk(h[6], h[7])};
                af[t] = x.b;
            }
            // acc init from C1'' / CSK (accumulator-init trick: saves epilogue FMAs)
            f32x4 acc1[4], accS[4];
            #pragma unroll
            for (int ct = 0; ct < 4; ++ct) {
                int c = ct * 16 + kidx;
                u32x2 cv1 = *(const u32x2*)(C1p + c * 68 + s * 16 + g * 4);
                u32x2 cvs = *(const u32x2*)(CSp + c * 68 + s * 16 + g * 4);
                acc1[ct] = (f32x4){bflo(cv1[0]), bfhi(cv1[0]), bflo(cv1[1]), bfhi(cv1[1])};
                accS[ct] = (f32x4){bflo(cvs[0]), bfhi(cvs[0]), bflo(cvs[1]), bfhi(cvs[1])};
            }
            // stage1 + skip GEMMs (s1a pre-folded into w1a)
            #pragma unroll
            for (int t = 0; t < 2; ++t)
                #pragma unroll
                for (int ct = 0; ct < 4; ++ct)
                    acc1[ct] = __builtin_amdgcn_mfma_f32_16x16x32_bf16(af[t], w1a[ct * 2 + t], acc1[ct], 0, 0, 0);
            #pragma unroll
            for (int t = 0; t < 2; ++t)
                #pragma unroll
                for (int ct = 0; ct < 4; ++ct)
                    accS[ct] = __builtin_amdgcn_mfma_f32_16x16x32_bf16(af[t], wsk[ct * 2 + t], accS[ct], 0, 0, 0);

            // h1 = relu(acc1) -> per-wave LDS (D-layout -> A-layout repack)
            #pragma unroll
            for (int ct = 0; ct < 4; ++ct) {
                int c = ct * 16 + kidx;
                u32 p01 = cvtpk(fmaxf(acc1[ct][0], 0.f), fmaxf(acc1[ct][1], 0.f));
                u32 p23 = cvtpk(fmaxf(acc1[ct][2], 0.f), fmaxf(acc1[ct][3], 0.f));
                h1p[(g * 4 + 0) * 72 + c] = (u16)p01;
                h1p[(g * 4 + 1) * 72 + c] = (u16)(p01 >> 16);
                h1p[(g * 4 + 2) * 72 + c] = (u16)p23;
                h1p[(g * 4 + 3) * 72 + c] = (u16)(p23 >> 16);
            }
            // stage2 GEMM from repacked h1 (s1b pre-folded into w1b)
            f32x4 acc2[4];
            #pragma unroll
            for (int ct = 0; ct < 4; ++ct) acc2[ct] = 0.f;
            #pragma unroll
            for (int t = 0; t < 2; ++t) {
                UU x; x.u = *(const u32x4*)(h1p + kidx * 72 + t * 32 + g * 8);
                #pragma unroll
                for (int ct = 0; ct < 4; ++ct)
                    acc2[ct] = __builtin_amdgcn_mfma_f32_16x16x32_bf16(x.b, w1b[ct * 2 + t], acc2[ct], 0, 0, 0);
            }
            // feat = accS + relu(acc2 + t1b);  running max over rows (k-points)
            #pragma unroll
            for (int ct = 0; ct < 4; ++ct) {
                #pragma unroll
                for (int r = 0; r < 4; ++r) {
                    float f = accS[ct][r] + fmaxf(acc2[ct][r] + t1b_r[ct], 0.f);
                    fmr[ct] = fmaxf(fmr[ct], f);
                }
            }
        }

        // finish pool across lane groups, then out = Wout @ [featmax; prexyz]
        #pragma unroll
        for (int ct = 0; ct < 4; ++ct) {
            fmr[ct] = fmaxf(fmr[ct], __shfl_xor(fmr[ct], 16));
            fmr[ct] = fmaxf(fmr[ct], __shfl_xor(fmr[ct], 32));
        }
        float po0 = 0.f, po1 = 0.f, po2 = 0.f;
        #pragma unroll
        for (int ct = 0; ct < 4; ++ct) {
            po0 += wo0[ct] * fmr[ct];
            po1 += wo1[ct] * fmr[ct];
            po2 += wo2[ct] * fmr[ct];
        }
        #pragma unroll
        for (int d = 1; d <= 8; d <<= 1) {
            po0 += __shfl_xor(po0, d);
            po1 += __shfl_xor(po1, d);
            po2 += __shfl_xor(po2, d);
        }
        if (l < 3) {
            float p0 = prexyz[(n * 3 + 0) * MT + m];
            float p1 = prexyz[(n * 3 + 1) * MT + m];
            float p2 = prexyz[(n * 3 + 2) * MT + m];
            float o = (l == 0) ? po0 : ((l == 1) ? po1 : po2);
            o += Wout[l * 67 + 64] * p0 + Wout[l * 67 + 65] * p1 + Wout[l * 67 + 66] * p2;
            out[(n * 3 + l) * MT + m] = o;
        }
    }
}

extern "C" void kernel_launch(void* const* d_in, const int* in_sizes, int n_in,
                              void* d_out, int out_size, void* d_ws, size_t ws_size,
                              hipStream_t stream) {
    const float* q    = (const float*)d_in[0];
    const float* srgb = (const float*)d_in[1];
    const float* sxyz = (const float*)d_in[2];
    const float* pxyz = (const float*)d_in[3];
    const float* mask = (const float*)d_in[4];
    const float* W0   = (const float*)d_in[5];
    const float* g0   = (const float*)d_in[6];
    const float* b0   = (const float*)d_in[7];
    const float* m0   = (const float*)d_in[8];
    const float* v0   = (const float*)d_in[9];
    const float* W1a  = (const float*)d_in[10];
    const float* g1a  = (const float*)d_in[11];
    const float* b1a  = (const float*)d_in[12];
    const float* m1a  = (const float*)d_in[13];
    const float* v1a  = (const float*)d_in[14];
    const float* W1b  = (const float*)d_in[15];
    const float* g1b  = (const float*)d_in[16];
    const float* b1b  = (const float*)d_in[17];
    const float* m1b  = (const float*)d_in[18];
    const float* v1b  = (const float*)d_in[19];
    const float* Wsk  = (const float*)d_in[20];
    const float* Wout = (const float*)d_in[21];
    float* out = (float*)d_out;

    hipLaunchKernelGGL(ctx_fused, dim3(600, 2), dim3(256), 0, stream,
        q, srgb, sxyz, pxyz, mask,
        W0, g0, b0, m0, v0,
        W1a, g1a, b1a, m1a, v1a,
        W1b, g1b, b1b, m1b, v1b,
        Wsk, Wout, out);
}